// Round 1
// baseline (853.294 us; speedup 1.0000x reference)
//
#include <hip/hip_runtime.h>
#include <math.h>

// Problem constants
// B=4, N=2048, C=384, H=8, HD=48, T=B*N=8192
// scale = 1/sqrt(48), RoPE base 100

// ---------------------------------------------------------------------------
// GEMM (NT): out[m,n] = sum_k A[m,k] * W[n,k] + bias[n]
// M=8192, Nn=384, K=384. Tiles 64x64x16, 256 threads, 4x4 per thread.
// ---------------------------------------------------------------------------
__global__ __launch_bounds__(256)
void gemm_nt_bias(const float* __restrict__ A, const float* __restrict__ W,
                  const float* __restrict__ bias, float* __restrict__ out,
                  int M, int Nn, int K)
{
    __shared__ float As[16][64];
    __shared__ float Bs[16][64];
    const int tid = threadIdx.x;
    const int m0 = blockIdx.x << 6;
    const int n0 = blockIdx.y << 6;
    const int lrow = tid >> 2;          // 0..63
    const int kg   = (tid & 3) << 2;    // 0,4,8,12
    const int ty = tid >> 4;            // 0..15 -> rows ty*4..+3
    const int tx = tid & 15;            // 0..15 -> cols tx*4..+3

    float acc[4][4] = {};
    const float* Ap = A + (size_t)(m0 + lrow) * K + kg;
    const float* Wp = W + (size_t)(n0 + lrow) * K + kg;

    for (int k0 = 0; k0 < K; k0 += 16) {
        const float4 av = *(const float4*)(Ap + k0);
        const float4 wv = *(const float4*)(Wp + k0);
        As[kg + 0][lrow] = av.x; As[kg + 1][lrow] = av.y;
        As[kg + 2][lrow] = av.z; As[kg + 3][lrow] = av.w;
        Bs[kg + 0][lrow] = wv.x; Bs[kg + 1][lrow] = wv.y;
        Bs[kg + 2][lrow] = wv.z; Bs[kg + 3][lrow] = wv.w;
        __syncthreads();
        #pragma unroll
        for (int kk = 0; kk < 16; ++kk) {
            const float4 a4 = *(const float4*)&As[kk][ty << 2];
            const float4 b4 = *(const float4*)&Bs[kk][tx << 2];
            const float aa[4] = {a4.x, a4.y, a4.z, a4.w};
            const float bb[4] = {b4.x, b4.y, b4.z, b4.w};
            #pragma unroll
            for (int i = 0; i < 4; ++i)
                #pragma unroll
                for (int j = 0; j < 4; ++j)
                    acc[i][j] = fmaf(aa[i], bb[j], acc[i][j]);
        }
        __syncthreads();
    }

    const float4 bsv = *(const float4*)&bias[n0 + (tx << 2)];
    const float bb[4] = {bsv.x, bsv.y, bsv.z, bsv.w};
    #pragma unroll
    for (int i = 0; i < 4; ++i) {
        float4 o;
        o.x = acc[i][0] + bb[0];
        o.y = acc[i][1] + bb[1];
        o.z = acc[i][2] + bb[2];
        o.w = acc[i][3] + bb[3];
        *(float4*)(out + (size_t)(m0 + (ty << 2) + i) * Nn + n0 + (tx << 2)) = o;
    }
}

// ---------------------------------------------------------------------------
// RoPE3D in-place on [T, C] projected q or k. grid.z: 0->q/qpos, 1->k/kpos.
// Each thread handles one rotation pair (j, j+8) within a 16-wide axis chunk.
// T*192 threads total per tensor.
// ---------------------------------------------------------------------------
__global__ __launch_bounds__(256)
void rope_kernel(float* __restrict__ qb, float* __restrict__ kb,
                 const int* __restrict__ qpos, const int* __restrict__ kpos)
{
    const int idx = blockIdx.x * 256 + threadIdx.x;  // 0 .. T*192-1
    float* x = (blockIdx.z == 0) ? qb : kb;
    const int* pos = (blockIdx.z == 0) ? qpos : kpos;
    const int t = idx / 192;
    const int p = idx - t * 192;
    const int h = p / 24;
    const int r = p - h * 24;
    const int axis = r >> 3;
    const int j = r & 7;
    const float pp = (float)pos[t * 3 + axis];
    // inv = 100^(-j/8) = exp(-j * ln(100)/8)
    const float inv = __expf(-(float)j * 0.57564627324851142f);
    float s, c;
    sincosf(pp * inv, &s, &c);
    float* base = x + (size_t)t * 384 + h * 48 + axis * 16 + j;
    const float x1 = base[0];
    const float x2 = base[8];
    base[0] = x1 * c - x2 * s;
    base[8] = x2 * c + x1 * s;
}

// ---------------------------------------------------------------------------
// Flash attention (fp32). One block: one (b,h), 64 queries. Iterates 32
// KV tiles of 64. Online softmax. P stored transposed in LDS (PT[kv][q]).
// Phase1: 4x4 reg-blocked QK^T (16x16 thread grid).
// Phase3: 4x4 reg-blocked PV (16 rowgroups x 12 colgroups = 192 threads).
// Output written to x2[t, h*48+d] ([T,C] layout) pre-normalized by l.
// ---------------------------------------------------------------------------
__global__ __launch_bounds__(256)
void attn_kernel(const float* __restrict__ qb, const float* __restrict__ kb,
                 const float* __restrict__ vb, float* __restrict__ x2)
{
    __shared__ float Qs[64][50];   // pad 50: even stride for float2 reads
    __shared__ float Ks[64][50];
    __shared__ float Vs[64][48];   // unpadded: broadcast reads, float4-aligned
    __shared__ float PT[64][68];   // P transposed [kv][q], pad 68 (16B-aligned rows)
    __shared__ float mrow[64], lrow[64], arow[64];
    __shared__ float red[64][4];

    const int tid = threadIdx.x;
    const int bh = blockIdx.y;
    const int b = bh >> 3;
    const int h = bh & 7;
    const int q0 = blockIdx.x << 6;
    const float scale = 0.14433756729740643f;  // 1/sqrt(48)

    const int lr = tid >> 2;            // 0..63 (loader row)
    const int ls = (tid & 3) * 12;      // loader col start
    const int ty = tid >> 4, tx = tid & 15;   // phase1 mapping
    const int r1 = tid & 63, qt = tid >> 6;   // phase2 mapping
    const int rg = tid / 12, cg = tid - (tid / 12) * 12;  // phase3 (tid<192)

    // load Q tile (64 x 48)
    {
        const float* src = qb + ((size_t)(b * 2048 + q0 + lr) * 384 + h * 48 + ls);
        const float4 a0 = *(const float4*)(src);
        const float4 a1 = *(const float4*)(src + 4);
        const float4 a2 = *(const float4*)(src + 8);
        float* dst = &Qs[lr][ls];
        dst[0] = a0.x; dst[1] = a0.y; dst[2]  = a0.z; dst[3]  = a0.w;
        dst[4] = a1.x; dst[5] = a1.y; dst[6]  = a1.z; dst[7]  = a1.w;
        dst[8] = a2.x; dst[9] = a2.y; dst[10] = a2.z; dst[11] = a2.w;
    }
    if (tid < 64) { mrow[tid] = -1e30f; lrow[tid] = 0.0f; }
    float o_acc[4][4] = {};

    const size_t kvbase = (size_t)(b * 2048) * 384 + h * 48;

    for (int kt = 0; kt < 32; ++kt) {
        __syncthreads();  // protect Ks/Vs/PT vs previous iteration's readers
        // load K and V tiles
        {
            const float* ksrc = kb + kvbase + (size_t)(kt * 64 + lr) * 384 + ls;
            const float4 a0 = *(const float4*)(ksrc);
            const float4 a1 = *(const float4*)(ksrc + 4);
            const float4 a2 = *(const float4*)(ksrc + 8);
            float* dst = &Ks[lr][ls];
            dst[0] = a0.x; dst[1] = a0.y; dst[2]  = a0.z; dst[3]  = a0.w;
            dst[4] = a1.x; dst[5] = a1.y; dst[6]  = a1.z; dst[7]  = a1.w;
            dst[8] = a2.x; dst[9] = a2.y; dst[10] = a2.z; dst[11] = a2.w;
            const float* vsrc = vb + kvbase + (size_t)(kt * 64 + lr) * 384 + ls;
            const float4 v0 = *(const float4*)(vsrc);
            const float4 v1 = *(const float4*)(vsrc + 4);
            const float4 v2 = *(const float4*)(vsrc + 8);
            float4* vdst = (float4*)&Vs[lr][ls];
            vdst[0] = v0; vdst[1] = v1; vdst[2] = v2;
        }
        __syncthreads();

        // phase1: S = scale * Q K^T -> PT[kv][q]
        float acc[4][4] = {};
        #pragma unroll
        for (int d = 0; d < 48; d += 2) {
            float2 qa[4], ka[4];
            #pragma unroll
            for (int i = 0; i < 4; ++i) qa[i] = *(const float2*)&Qs[(ty << 2) + i][d];
            #pragma unroll
            for (int j = 0; j < 4; ++j) ka[j] = *(const float2*)&Ks[(tx << 2) + j][d];
            #pragma unroll
            for (int i = 0; i < 4; ++i)
                #pragma unroll
                for (int j = 0; j < 4; ++j) {
                    acc[i][j] = fmaf(qa[i].x, ka[j].x, acc[i][j]);
                    acc[i][j] = fmaf(qa[i].y, ka[j].y, acc[i][j]);
                }
        }
        #pragma unroll
        for (int j = 0; j < 4; ++j)
            #pragma unroll
            for (int i = 0; i < 4; ++i)
                PT[(tx << 2) + j][(ty << 2) + i] = acc[i][j] * scale;
        __syncthreads();

        // phase2: online softmax. (r1, qt): 16 kv entries each.
        float mx = -1e30f;
        #pragma unroll
        for (int kv = qt * 16; kv < qt * 16 + 16; ++kv) mx = fmaxf(mx, PT[kv][r1]);
        red[r1][qt] = mx;
        __syncthreads();
        if (tid < 64) {
            const float mo = mrow[tid];
            float mn = fmaxf(fmaxf(red[tid][0], red[tid][1]),
                             fmaxf(red[tid][2], red[tid][3]));
            mn = fmaxf(mo, mn);
            mrow[tid] = mn;
            arow[tid] = __expf(mo - mn);
        }
        __syncthreads();
        const float mn = mrow[r1];
        float psum = 0.0f;
        #pragma unroll
        for (int kv = qt * 16; kv < qt * 16 + 16; ++kv) {
            const float pe = __expf(PT[kv][r1] - mn);
            PT[kv][r1] = pe;
            psum += pe;
        }
        red[r1][qt] = psum;
        __syncthreads();
        if (tid < 64)
            lrow[tid] = lrow[tid] * arow[tid] +
                        red[tid][0] + red[tid][1] + red[tid][2] + red[tid][3];

        // phase3: O = O*alpha + P V  (192 active threads, 4 rows x 4 cols each)
        if (tid < 192) {
            #pragma unroll
            for (int i = 0; i < 4; ++i) {
                const float al = arow[(rg << 2) + i];
                #pragma unroll
                for (int j = 0; j < 4; ++j) o_acc[i][j] *= al;
            }
            for (int kv = 0; kv < 64; ++kv) {
                const float4 pv = *(const float4*)&PT[kv][rg << 2];
                const float4 vv = *(const float4*)&Vs[kv][cg << 2];
                const float pa[4] = {pv.x, pv.y, pv.z, pv.w};
                const float va[4] = {vv.x, vv.y, vv.z, vv.w};
                #pragma unroll
                for (int i = 0; i < 4; ++i)
                    #pragma unroll
                    for (int j = 0; j < 4; ++j)
                        o_acc[i][j] = fmaf(pa[i], va[j], o_acc[i][j]);
            }
        }
    }
    __syncthreads();  // lrow final values
    if (tid < 192) {
        #pragma unroll
        for (int i = 0; i < 4; ++i) {
            const float invl = 1.0f / lrow[(rg << 2) + i];
            float4 o;
            o.x = o_acc[i][0] * invl;
            o.y = o_acc[i][1] * invl;
            o.z = o_acc[i][2] * invl;
            o.w = o_acc[i][3] * invl;
            *(float4*)(x2 + ((size_t)(b * 2048 + q0 + (rg << 2) + i) * 384 +
                             h * 48 + (cg << 2))) = o;
        }
    }
}

// ---------------------------------------------------------------------------
extern "C" void kernel_launch(void* const* d_in, const int* in_sizes, int n_in,
                              void* d_out, int out_size, void* d_ws, size_t ws_size,
                              hipStream_t stream)
{
    const float* query = (const float*)d_in[0];
    const float* key_  = (const float*)d_in[1];
    const float* value = (const float*)d_in[2];
    const float* Wq = (const float*)d_in[3];
    const float* bq = (const float*)d_in[4];
    const float* Wk = (const float*)d_in[5];
    const float* bk = (const float*)d_in[6];
    const float* Wv = (const float*)d_in[7];
    const float* bv = (const float*)d_in[8];
    const float* Wo = (const float*)d_in[9];
    const float* bo = (const float*)d_in[10];
    const int* qpos = (const int*)d_in[11];
    const int* kpos = (const int*)d_in[12];
    // d_in[13], d_in[14]: equal-segment offsets, unused (B,N hardcoded)

    const size_t TC = (size_t)8192 * 384;
    float* ws = (float*)d_ws;
    float *qbuf, *kbuf, *vbuf, *x2;
    if (ws_size >= 4 * TC * sizeof(float)) {
        qbuf = ws; kbuf = ws + TC; vbuf = ws + 2 * TC; x2 = ws + 3 * TC;
    } else {
        // fall back: use d_out as q scratch (overwritten only by the final GEMM,
        // which runs after attention has consumed qbuf — stream-ordered safe)
        qbuf = (float*)d_out; kbuf = ws; vbuf = ws + TC; x2 = ws + 2 * TC;
    }

    const dim3 blk(256);
    const dim3 ggrid(8192 / 64, 384 / 64, 1);
    gemm_nt_bias<<<ggrid, blk, 0, stream>>>(query, Wq, bq, qbuf, 8192, 384, 384);
    gemm_nt_bias<<<ggrid, blk, 0, stream>>>(key_,  Wk, bk, kbuf, 8192, 384, 384);
    gemm_nt_bias<<<ggrid, blk, 0, stream>>>(value, Wv, bv, vbuf, 8192, 384, 384);
    rope_kernel<<<dim3(8192 * 192 / 256, 1, 2), blk, 0, stream>>>(qbuf, kbuf, qpos, kpos);
    attn_kernel<<<dim3(2048 / 64, 32, 1), blk, 0, stream>>>(qbuf, kbuf, vbuf, x2);
    gemm_nt_bias<<<ggrid, blk, 0, stream>>>(x2, Wo, bo, (float*)d_out, 8192, 384, 384);
}

// Round 2
// 481.349 us; speedup vs baseline: 1.7727x; 1.7727x over previous
//
#include <hip/hip_runtime.h>
#include <math.h>

// B=4, N=2048, C=384, H=8, HD=48, T=8192. scale=1/sqrt(48). RoPE base 100.

typedef __attribute__((ext_vector_type(8))) short bf16x8;
typedef __attribute__((ext_vector_type(4))) float f32x4;

__device__ inline short f2bf(float f) {
    unsigned u = __float_as_uint(f);
    u += 0x7fffu + ((u >> 16) & 1u);   // round-to-nearest-even
    return (short)(u >> 16);
}

// ---------------------------------------------------------------------------
// GEMM (NT): out[m,n] = sum_k A[m,k]*W[n,k] + bias[n]. 64x64x16 tiles, fp32.
// ---------------------------------------------------------------------------
__global__ __launch_bounds__(256)
void gemm_nt_bias(const float* __restrict__ A, const float* __restrict__ W,
                  const float* __restrict__ bias, float* __restrict__ out,
                  int M, int Nn, int K)
{
    __shared__ float As[16][64];
    __shared__ float Bs[16][64];
    const int tid = threadIdx.x;
    const int m0 = blockIdx.x << 6;
    const int n0 = blockIdx.y << 6;
    const int lrow = tid >> 2;
    const int kg   = (tid & 3) << 2;
    const int ty = tid >> 4;
    const int tx = tid & 15;

    float acc[4][4] = {};
    const float* Ap = A + (size_t)(m0 + lrow) * K + kg;
    const float* Wp = W + (size_t)(n0 + lrow) * K + kg;

    for (int k0 = 0; k0 < K; k0 += 16) {
        const float4 av = *(const float4*)(Ap + k0);
        const float4 wv = *(const float4*)(Wp + k0);
        As[kg + 0][lrow] = av.x; As[kg + 1][lrow] = av.y;
        As[kg + 2][lrow] = av.z; As[kg + 3][lrow] = av.w;
        Bs[kg + 0][lrow] = wv.x; Bs[kg + 1][lrow] = wv.y;
        Bs[kg + 2][lrow] = wv.z; Bs[kg + 3][lrow] = wv.w;
        __syncthreads();
        #pragma unroll
        for (int kk = 0; kk < 16; ++kk) {
            const float4 a4 = *(const float4*)&As[kk][ty << 2];
            const float4 b4 = *(const float4*)&Bs[kk][tx << 2];
            const float aa[4] = {a4.x, a4.y, a4.z, a4.w};
            const float bb[4] = {b4.x, b4.y, b4.z, b4.w};
            #pragma unroll
            for (int i = 0; i < 4; ++i)
                #pragma unroll
                for (int j = 0; j < 4; ++j)
                    acc[i][j] = fmaf(aa[i], bb[j], acc[i][j]);
        }
        __syncthreads();
    }

    const float4 bsv = *(const float4*)&bias[n0 + (tx << 2)];
    const float bb[4] = {bsv.x, bsv.y, bsv.z, bsv.w};
    #pragma unroll
    for (int i = 0; i < 4; ++i) {
        float4 o;
        o.x = acc[i][0] + bb[0];
        o.y = acc[i][1] + bb[1];
        o.z = acc[i][2] + bb[2];
        o.w = acc[i][3] + bb[3];
        *(float4*)(out + (size_t)(m0 + (ty << 2) + i) * Nn + n0 + (tx << 2)) = o;
    }
}

// ---------------------------------------------------------------------------
// RoPE + fp32->bf16 convert. Reads [T,384] fp32, writes [B*H,2048,64] bf16
// (HD padded 48->64; pad zeroed beforehand by hipMemsetAsync).
// grid.z: 0 -> q, 1 -> k. One thread per rotation pair.
// ---------------------------------------------------------------------------
__global__ __launch_bounds__(256)
void rope_convert(const float* __restrict__ qbuf, const float* __restrict__ kbuf,
                  const int* __restrict__ qpos, const int* __restrict__ kpos,
                  short* __restrict__ qbf, short* __restrict__ kbf)
{
    const int idx = blockIdx.x * 256 + threadIdx.x;   // 0 .. T*192-1
    const float* x = (blockIdx.z == 0) ? qbuf : kbuf;
    const int* pos = (blockIdx.z == 0) ? qpos : kpos;
    short* o = (blockIdx.z == 0) ? qbf : kbf;
    const int t = idx / 192;
    const int p = idx - t * 192;
    const int h = p / 24;
    const int r = p - h * 24;
    const int axis = r >> 3;
    const int j = r & 7;
    const float pp = (float)pos[t * 3 + axis];
    const float inv = __expf(-(float)j * 0.57564627324851142f);  // 100^(-j/8)
    float s, c;
    sincosf(pp * inv, &s, &c);
    const float* src = x + (size_t)t * 384 + h * 48 + axis * 16 + j;
    const float x1 = src[0], x2 = src[8];
    const int b = t >> 11, n = t & 2047;
    short* dst = o + (((size_t)(b * 8 + h) * 2048) + n) * 64 + axis * 16 + j;
    dst[0] = f2bf(x1 * c - x2 * s);
    dst[8] = f2bf(x2 * c + x1 * s);
}

// ---------------------------------------------------------------------------
// V transpose + convert: [T,384] fp32 -> [B*H,48,2048] bf16 (Vt[d][n]).
// ---------------------------------------------------------------------------
__global__ __launch_bounds__(256)
void v_transpose(const float* __restrict__ vbuf, short* __restrict__ vtbf)
{
    const int idx = blockIdx.x * 256 + threadIdx.x;   // bh*48*2048 + d*2048 + n
    const int n = idx & 2047;
    const int dh = idx >> 11;
    const int d = dh % 48;
    const int bh = dh / 48;
    const float v = vbuf[((size_t)((bh >> 3) * 2048 + n)) * 384 + (bh & 7) * 48 + d];
    vtbf[idx] = f2bf(v);
}

// ---------------------------------------------------------------------------
// Flash attention, bf16 MFMA 16x16x32, barrier-free.
// Block = 4 waves; wave w owns q rows [q0+16w, q0+16w+16). 32 kv tiles of 64.
// Q/K fragments from qbf/kbf [bh][n][64]; V fragments from vtbf [bh][d][2048].
// Softmax fully in-register (shfl_xor over the 16-lane col groups).
// P does C-layout -> A-layout round trip through a per-wave LDS strip.
// ---------------------------------------------------------------------------
__global__ __launch_bounds__(256)
void attn_mfma(const short* __restrict__ qbf, const short* __restrict__ kbf,
               const short* __restrict__ vtbf, float* __restrict__ x2)
{
    __shared__ short Ps[4][16][72];   // pad 72: rows 144B (16B-aligned b128 reads)
    const int tid = threadIdx.x;
    const int wave = tid >> 6;
    const int lane = tid & 63;
    const int l15 = lane & 15;
    const int quad = lane >> 4;
    const int bh = blockIdx.y;
    const int q0 = blockIdx.x << 6;
    const float scale = 0.14433756729740643f;  // 1/sqrt(48)

    // Q A-fragments: A[m=l15][k=quad*8+j], two 32-wide K steps (d 0..31, 32..63)
    const short* qptr = qbf + (((size_t)bh * 2048) + q0 + wave * 16 + l15) * 64 + quad * 8;
    const bf16x8 qa0 = *(const bf16x8*)qptr;
    const bf16x8 qa1 = *(const bf16x8*)(qptr + 32);

    f32x4 of[3];
    #pragma unroll
    for (int t = 0; t < 3; ++t) of[t] = (f32x4){0.f, 0.f, 0.f, 0.f};
    float m_r[4] = {-1e30f, -1e30f, -1e30f, -1e30f};
    float l_r[4] = {0.f, 0.f, 0.f, 0.f};

    const short* kb0 = kbf + ((size_t)bh * 2048) * 64 + (size_t)l15 * 64 + quad * 8;
    const short* vt0 = vtbf + ((size_t)bh * 48 + l15) * 2048 + quad * 8;

    for (int kt = 0; kt < 32; ++kt) {
        // K B-fragments: B[n=kv_local=l15][k=d=quad*8+j]; 4 n-tiles x 2 ksteps
        bf16x8 kb[4][2], vb[3][2];
        const short* kp = kb0 + (size_t)kt * 64 * 64;
        #pragma unroll
        for (int t = 0; t < 4; ++t)
            #pragma unroll
            for (int s = 0; s < 2; ++s)
                kb[t][s] = *(const bf16x8*)(kp + t * 16 * 64 + s * 32);
        // V B-fragments: B[n=d_local=l15][k=kv=quad*8+j] from Vt[d][n]
        const short* vp = vt0 + kt * 64;
        #pragma unroll
        for (int t = 0; t < 3; ++t)
            #pragma unroll
            for (int s = 0; s < 2; ++s)
                vb[t][s] = *(const bf16x8*)(vp + (size_t)t * 16 * 2048 + s * 32);

        // S = Q K^T  (C rows = q_local quad*4+r, cols = kv_local l15 + 16t)
        f32x4 sf[4];
        #pragma unroll
        for (int t = 0; t < 4; ++t) {
            f32x4 z = (f32x4){0.f, 0.f, 0.f, 0.f};
            z = __builtin_amdgcn_mfma_f32_16x16x32_bf16(qa0, kb[t][0], z, 0, 0, 0);
            sf[t] = __builtin_amdgcn_mfma_f32_16x16x32_bf16(qa1, kb[t][1], z, 0, 0, 0);
        }

        // row max over 64 kv (4 reg-tiles, then 16-lane butterfly)
        float alpha[4];
        #pragma unroll
        for (int r = 0; r < 4; ++r) {
            float a = fmaxf(fmaxf(sf[0][r], sf[1][r]), fmaxf(sf[2][r], sf[3][r]));
            a *= scale;
            #pragma unroll
            for (int off = 1; off < 16; off <<= 1)
                a = fmaxf(a, __shfl_xor(a, off));
            const float mn = fmaxf(m_r[r], a);
            alpha[r] = __expf(m_r[r] - mn);
            m_r[r] = mn;
        }

        // p = exp(scale*s - m); store bf16 P strip (C-order write)
        float rs[4] = {0.f, 0.f, 0.f, 0.f};
        #pragma unroll
        for (int t = 0; t < 4; ++t)
            #pragma unroll
            for (int r = 0; r < 4; ++r) {
                const float p = __expf(fmaf(sf[t][r], scale, -m_r[r]));
                rs[r] += p;
                Ps[wave][quad * 4 + r][t * 16 + l15] = f2bf(p);
            }
        #pragma unroll
        for (int r = 0; r < 4; ++r) {
            float a = rs[r];
            #pragma unroll
            for (int off = 1; off < 16; off <<= 1)
                a += __shfl_xor(a, off);
            l_r[r] = l_r[r] * alpha[r] + a;
        }

        // rescale O, then O += P V  (P read back in A-layout from own strip;
        // intra-wave LDS ops are in-order, no barrier needed)
        #pragma unroll
        for (int t = 0; t < 3; ++t)
            #pragma unroll
            for (int r = 0; r < 4; ++r)
                of[t][r] *= alpha[r];
        const bf16x8 pa0 = *(const bf16x8*)&Ps[wave][l15][quad * 8];
        const bf16x8 pa1 = *(const bf16x8*)&Ps[wave][l15][32 + quad * 8];
        #pragma unroll
        for (int t = 0; t < 3; ++t) {
            of[t] = __builtin_amdgcn_mfma_f32_16x16x32_bf16(pa0, vb[t][0], of[t], 0, 0, 0);
            of[t] = __builtin_amdgcn_mfma_f32_16x16x32_bf16(pa1, vb[t][1], of[t], 0, 0, 0);
        }
    }

    // epilogue: normalize and write x2 [T,384] fp32
    const int b = bh >> 3, h = bh & 7;
    #pragma unroll
    for (int r = 0; r < 4; ++r) {
        const float inv = 1.0f / l_r[r];
        float* orow = x2 + (size_t)(b * 2048 + q0 + wave * 16 + quad * 4 + r) * 384
                         + h * 48 + l15;
        #pragma unroll
        for (int t = 0; t < 3; ++t)
            orow[t * 16] = of[t][r] * inv;
    }
}

// ---------------------------------------------------------------------------
extern "C" void kernel_launch(void* const* d_in, const int* in_sizes, int n_in,
                              void* d_out, int out_size, void* d_ws, size_t ws_size,
                              hipStream_t stream)
{
    const float* query = (const float*)d_in[0];
    const float* key_  = (const float*)d_in[1];
    const float* value = (const float*)d_in[2];
    const float* Wq = (const float*)d_in[3];
    const float* bq = (const float*)d_in[4];
    const float* Wk = (const float*)d_in[5];
    const float* bk = (const float*)d_in[6];
    const float* Wv = (const float*)d_in[7];
    const float* bv = (const float*)d_in[8];
    const float* Wo = (const float*)d_in[9];
    const float* bo = (const float*)d_in[10];
    const int* qpos = (const int*)d_in[11];
    const int* kpos = (const int*)d_in[12];

    const size_t TC = (size_t)8192 * 384;           // fp32 elements
    const size_t QK_BF = (size_t)32 * 2048 * 64;    // bf16 elements (padded q/k)
    const size_t VT_BF = (size_t)32 * 48 * 2048;    // bf16 elements (Vt)
    const size_t need1 = 3 * TC * 4 + (2 * QK_BF + VT_BF) * 2;

    float *qbuf, *kbuf, *vbuf, *x2;
    short *qbf, *kbf, *vtbf;
    char* w = (char*)d_ws;
    if (ws_size >= need1) {
        qbuf = (float*)w;  w += TC * 4;
        kbuf = (float*)w;  w += TC * 4;
        vbuf = (float*)w;  w += TC * 4;
        qbf  = (short*)w;  w += QK_BF * 2;
        kbf  = (short*)w;  w += QK_BF * 2;
        vtbf = (short*)w;
    } else {
        // q fp32 scratch in d_out (dead before final GEMM writes d_out)
        qbuf = (float*)d_out;
        kbuf = (float*)w;  w += TC * 4;
        vbuf = (float*)w;  w += TC * 4;
        qbf  = (short*)w;  w += QK_BF * 2;
        kbf  = (short*)w;  w += QK_BF * 2;
        vtbf = (short*)w;
    }
    x2 = vbuf;  // vbuf dead after v_transpose; attn output reuses it

    const dim3 blk(256);
    const dim3 ggrid(8192 / 64, 384 / 64, 1);
    gemm_nt_bias<<<ggrid, blk, 0, stream>>>(query, Wq, bq, qbuf, 8192, 384, 384);
    gemm_nt_bias<<<ggrid, blk, 0, stream>>>(key_,  Wk, bk, kbuf, 8192, 384, 384);
    gemm_nt_bias<<<ggrid, blk, 0, stream>>>(value, Wv, bv, vbuf, 8192, 384, 384);
    hipMemsetAsync(qbf, 0, QK_BF * 2, stream);   // zero HD pad 48..63
    hipMemsetAsync(kbf, 0, QK_BF * 2, stream);
    rope_convert<<<dim3(8192 * 192 / 256, 1, 2), blk, 0, stream>>>(
        qbuf, kbuf, qpos, kpos, qbf, kbf);
    v_transpose<<<dim3((unsigned)(VT_BF / 256)), blk, 0, stream>>>(vbuf, vtbf);
    attn_mfma<<<dim3(2048 / 64, 32, 1), blk, 0, stream>>>(qbf, kbf, vtbf, x2);
    gemm_nt_bias<<<ggrid, blk, 0, stream>>>(x2, Wo, bo, (float*)d_out, 8192, 384, 384);
}

// Round 3
// 363.878 us; speedup vs baseline: 2.3450x; 1.3228x over previous
//
#include <hip/hip_runtime.h>
#include <math.h>

// B=4, N=2048, C=384, H=8, HD=48, T=8192. scale=1/sqrt(48). RoPE base 100.

typedef __attribute__((ext_vector_type(8))) short bf16x8;
typedef __attribute__((ext_vector_type(4))) float f32x4;
typedef __attribute__((ext_vector_type(4))) short s16x4;

__device__ inline short f2bf(float f) {
    unsigned u = __float_as_uint(f);
    u += 0x7fffu + ((u >> 16) & 1u);   // RNE
    return (short)(u >> 16);
}
__device__ inline float exp2f_fast(float x) {
#if __has_builtin(__builtin_amdgcn_exp2f)
    return __builtin_amdgcn_exp2f(x);
#else
    return exp2f(x);
#endif
}
// h = c / 48 for c < 384
__device__ inline int div48(int c) { return (c * 683) >> 15; }

// ---------------------------------------------------------------------------
// Fused GEMM (NT) + RoPE + bf16 pack for Q and K.
// out bf16 layout: [B*H, 2048, 48].  blockIdx.z: 0 -> q, 1 -> k.
// ---------------------------------------------------------------------------
__global__ __launch_bounds__(256)
void gemm_qk_rope(const float* __restrict__ q_in, const float* __restrict__ k_in,
                  const float* __restrict__ Wq, const float* __restrict__ bq,
                  const float* __restrict__ Wk, const float* __restrict__ bk,
                  const int* __restrict__ qpos, const int* __restrict__ kpos,
                  short* __restrict__ qbf, short* __restrict__ kbf)
{
    const float* A    = blockIdx.z ? k_in : q_in;
    const float* W    = blockIdx.z ? Wk   : Wq;
    const float* bias = blockIdx.z ? bk   : bq;
    const int*   pos  = blockIdx.z ? kpos : qpos;
    short*       obf  = blockIdx.z ? kbf  : qbf;

    __shared__ float As[16][64];
    __shared__ float Bs[16][64];
    const int tid = threadIdx.x;
    const int m0 = blockIdx.x << 6;
    const int n0 = blockIdx.y << 6;
    const int lrow = tid >> 2;
    const int kg   = (tid & 3) << 2;
    const int ty = tid >> 4;
    const int tx = tid & 15;

    float acc[4][4] = {};
    const float* Ap = A + (size_t)(m0 + lrow) * 384 + kg;
    const float* Wp = W + (size_t)(n0 + lrow) * 384 + kg;

    for (int k0 = 0; k0 < 384; k0 += 16) {
        const float4 av = *(const float4*)(Ap + k0);
        const float4 wv = *(const float4*)(Wp + k0);
        As[kg + 0][lrow] = av.x; As[kg + 1][lrow] = av.y;
        As[kg + 2][lrow] = av.z; As[kg + 3][lrow] = av.w;
        Bs[kg + 0][lrow] = wv.x; Bs[kg + 1][lrow] = wv.y;
        Bs[kg + 2][lrow] = wv.z; Bs[kg + 3][lrow] = wv.w;
        __syncthreads();
        #pragma unroll
        for (int kk = 0; kk < 16; ++kk) {
            const float4 a4 = *(const float4*)&As[kk][ty << 2];
            const float4 b4 = *(const float4*)&Bs[kk][tx << 2];
            const float aa[4] = {a4.x, a4.y, a4.z, a4.w};
            const float bb[4] = {b4.x, b4.y, b4.z, b4.w};
            #pragma unroll
            for (int i = 0; i < 4; ++i)
                #pragma unroll
                for (int j = 0; j < 4; ++j)
                    acc[i][j] = fmaf(aa[i], bb[j], acc[i][j]);
        }
        __syncthreads();
    }

    // epilogue: bias + RoPE + bf16 pack.  4 consecutive channels per thread,
    // never straddling a head (48 % 4 == 0) nor an axis-16 chunk.
    const int c0 = n0 + (tx << 2);
    const int h  = div48(c0);
    const int r0 = c0 - h * 48;           // 0..44, 4-aligned
    const int axis = r0 >> 4;
    const float4 bsv = *(const float4*)&bias[c0];
    const float bb[4] = {bsv.x, bsv.y, bsv.z, bsv.w};
    // per-j rotation coefficient 100^(-m8/8) = 2^(-m8 * log2(100)/8)
    float invf[4];
    #pragma unroll
    for (int j = 0; j < 4; ++j) {
        const int m8 = ((r0 & 15) + j) & 7;
        invf[j] = exp2f_fast(-(float)m8 * 0.8304820237218405f);
    }
    #pragma unroll
    for (int i = 0; i < 4; ++i) {
        const int t = m0 + (ty << 2) + i;
        const float pp = (float)pos[t * 3 + axis];
        s16x4 pk;
        #pragma unroll
        for (int j = 0; j < 4; ++j) {
            const float v = acc[i][j] + bb[j];
            const float partner = __shfl_xor(v, 2);   // channel c ^ 8
            const int jj = (r0 & 15) + j;             // 0..15 in chunk
            float s, c;
            sincosf(pp * invf[j], &s, &c);
            const float o = (jj < 8) ? (v * c - partner * s)
                                     : (v * c + partner * s);
            ((short*)&pk)[j] = f2bf(o);
        }
        const int b = t >> 11, n = t & 2047;
        *(s16x4*)(obf + (((size_t)(b * 8 + h) * 2048) + n) * 48 + r0) = pk;
    }
}

// ---------------------------------------------------------------------------
// Fused GEMM (NT) + transposed bf16 pack for V: out [B*H, 48, 2048].
// ---------------------------------------------------------------------------
__global__ __launch_bounds__(256)
void gemm_v_t(const float* __restrict__ A, const float* __restrict__ W,
              const float* __restrict__ bias, short* __restrict__ vtbf)
{
    __shared__ float As[16][64];
    __shared__ float Bs[16][64];
    const int tid = threadIdx.x;
    const int m0 = blockIdx.x << 6;
    const int n0 = blockIdx.y << 6;
    const int lrow = tid >> 2;
    const int kg   = (tid & 3) << 2;
    const int ty = tid >> 4;
    const int tx = tid & 15;

    float acc[4][4] = {};
    const float* Ap = A + (size_t)(m0 + lrow) * 384 + kg;
    const float* Wp = W + (size_t)(n0 + lrow) * 384 + kg;

    for (int k0 = 0; k0 < 384; k0 += 16) {
        const float4 av = *(const float4*)(Ap + k0);
        const float4 wv = *(const float4*)(Wp + k0);
        As[kg + 0][lrow] = av.x; As[kg + 1][lrow] = av.y;
        As[kg + 2][lrow] = av.z; As[kg + 3][lrow] = av.w;
        Bs[kg + 0][lrow] = wv.x; Bs[kg + 1][lrow] = wv.y;
        Bs[kg + 2][lrow] = wv.z; Bs[kg + 3][lrow] = wv.w;
        __syncthreads();
        #pragma unroll
        for (int kk = 0; kk < 16; ++kk) {
            const float4 a4 = *(const float4*)&As[kk][ty << 2];
            const float4 b4 = *(const float4*)&Bs[kk][tx << 2];
            const float aa[4] = {a4.x, a4.y, a4.z, a4.w};
            const float bb[4] = {b4.x, b4.y, b4.z, b4.w};
            #pragma unroll
            for (int i = 0; i < 4; ++i)
                #pragma unroll
                for (int j = 0; j < 4; ++j)
                    acc[i][j] = fmaf(aa[i], bb[j], acc[i][j]);
        }
        __syncthreads();
    }

    const int c0 = n0 + (tx << 2);
    const int h  = div48(c0);
    const int r0 = c0 - h * 48;
    const float4 bsv = *(const float4*)&bias[c0];
    const float bb[4] = {bsv.x, bsv.y, bsv.z, bsv.w};
    const int t0 = m0 + (ty << 2);
    const int b = t0 >> 11, n = t0 & 2047;   // 4 rows share b (m0 64-aligned)
    #pragma unroll
    for (int j = 0; j < 4; ++j) {
        s16x4 pk;
        #pragma unroll
        for (int i = 0; i < 4; ++i)
            ((short*)&pk)[i] = f2bf(acc[i][j] + bb[j]);
        *(s16x4*)(vtbf + (((size_t)(b * 8 + h) * 48) + r0 + j) * 2048 + n) = pk;
    }
}

// ---------------------------------------------------------------------------
// Plain fp32 GEMM (NT) + bias for the output projection.
// ---------------------------------------------------------------------------
__global__ __launch_bounds__(256)
void gemm_nt_bias(const float* __restrict__ A, const float* __restrict__ W,
                  const float* __restrict__ bias, float* __restrict__ out)
{
    __shared__ float As[16][64];
    __shared__ float Bs[16][64];
    const int tid = threadIdx.x;
    const int m0 = blockIdx.x << 6;
    const int n0 = blockIdx.y << 6;
    const int lrow = tid >> 2;
    const int kg   = (tid & 3) << 2;
    const int ty = tid >> 4;
    const int tx = tid & 15;

    float acc[4][4] = {};
    const float* Ap = A + (size_t)(m0 + lrow) * 384 + kg;
    const float* Wp = W + (size_t)(n0 + lrow) * 384 + kg;

    for (int k0 = 0; k0 < 384; k0 += 16) {
        const float4 av = *(const float4*)(Ap + k0);
        const float4 wv = *(const float4*)(Wp + k0);
        As[kg + 0][lrow] = av.x; As[kg + 1][lrow] = av.y;
        As[kg + 2][lrow] = av.z; As[kg + 3][lrow] = av.w;
        Bs[kg + 0][lrow] = wv.x; Bs[kg + 1][lrow] = wv.y;
        Bs[kg + 2][lrow] = wv.z; Bs[kg + 3][lrow] = wv.w;
        __syncthreads();
        #pragma unroll
        for (int kk = 0; kk < 16; ++kk) {
            const float4 a4 = *(const float4*)&As[kk][ty << 2];
            const float4 b4 = *(const float4*)&Bs[kk][tx << 2];
            const float aa[4] = {a4.x, a4.y, a4.z, a4.w};
            const float bb[4] = {b4.x, b4.y, b4.z, b4.w};
            #pragma unroll
            for (int i = 0; i < 4; ++i)
                #pragma unroll
                for (int j = 0; j < 4; ++j)
                    acc[i][j] = fmaf(aa[i], bb[j], acc[i][j]);
        }
        __syncthreads();
    }

    const float4 bsv = *(const float4*)&bias[n0 + (tx << 2)];
    const float bb[4] = {bsv.x, bsv.y, bsv.z, bsv.w};
    #pragma unroll
    for (int i = 0; i < 4; ++i) {
        float4 o;
        o.x = acc[i][0] + bb[0];
        o.y = acc[i][1] + bb[1];
        o.z = acc[i][2] + bb[2];
        o.w = acc[i][3] + bb[3];
        *(float4*)(out + (size_t)(m0 + (ty << 2) + i) * 384 + n0 + (tx << 2)) = o;
    }
}

// ---------------------------------------------------------------------------
// Flash attention, transposed orientation (S^T = K Q^T, O^T = V^T P^T).
// Wave owns 16 q rows; 16 iterations of 128 kv. Softmax state per-lane
// scalar (q = lane&15). Barrier-free: per-wave private P strip in LDS.
// K=48 handled as K=32 MFMA + half-zero K=16 fragments (no memory padding).
// ---------------------------------------------------------------------------
__global__ __launch_bounds__(256)
void attn_mfma(const short* __restrict__ qbf, const short* __restrict__ kbf,
               const short* __restrict__ vtbf, float* __restrict__ x2)
{
    __shared__ short Ps[4][16][136];   // [wave][q][kv 0..127], stride 272B (16B-mult)
    const int tid = threadIdx.x;
    const int wave = tid >> 6;
    const int lane = tid & 63;
    const int l15 = lane & 15;
    const int quad = lane >> 4;
    const int bh = blockIdx.y;
    const int q0 = blockIdx.x << 6;
    const float s2 = 0.2082339551542919f;  // (1/sqrt(48)) * log2(e)

    // Q B-fragments: B[n=q=l15][k=d]
    const short* qp = qbf + ((size_t)bh * 2048 + q0 + wave * 16 + l15) * 48 + quad * 8;
    const bf16x8 qb0 = *(const bf16x8*)qp;
    bf16x8 qb1 = {0, 0, 0, 0, 0, 0, 0, 0};
    if (quad < 2) qb1 = *(const bf16x8*)(qp + 32);   // d = 32+quad*8 .. +7

    f32x4 of[3];
    #pragma unroll
    for (int t = 0; t < 3; ++t) of[t] = (f32x4){0.f, 0.f, 0.f, 0.f};
    float m2 = -1e30f, l_r = 0.f;

    const short* kbase = kbf + ((size_t)bh * 2048) * 48;
    const short* vbase = vtbf + ((size_t)bh * 48 + l15) * 2048 + quad * 8;

    for (int kt = 0; kt < 16; ++kt) {
        // ---- S^T = K Q^T over 8 kv tiles of 16 (two groups of 4) ----
        f32x4 sf[8];
        #pragma unroll
        for (int g = 0; g < 2; ++g) {
            bf16x8 ka0[4], ka1[4];
            #pragma unroll
            for (int t = 0; t < 4; ++t) {
                const short* kp = kbase +
                    ((size_t)(kt * 128 + (g * 4 + t) * 16 + l15)) * 48 + quad * 8;
                ka0[t] = *(const bf16x8*)kp;
                ka1[t] = (bf16x8){0, 0, 0, 0, 0, 0, 0, 0};
                if (quad < 2) ka1[t] = *(const bf16x8*)(kp + 32);
            }
            #pragma unroll
            for (int t = 0; t < 4; ++t) {
                f32x4 z = (f32x4){0.f, 0.f, 0.f, 0.f};
                z = __builtin_amdgcn_mfma_f32_16x16x32_bf16(ka0[t], qb0, z, 0, 0, 0);
                sf[g * 4 + t] =
                    __builtin_amdgcn_mfma_f32_16x16x32_bf16(ka1[t], qb1, z, 0, 0, 0);
            }
        }

        // ---- online softmax (per-lane q; reduce over quads only) ----
        float mx = -1e30f;
        #pragma unroll
        for (int t = 0; t < 8; ++t)
            #pragma unroll
            for (int r = 0; r < 4; ++r) mx = fmaxf(mx, sf[t][r]);
        mx *= s2;
        mx = fmaxf(mx, __shfl_xor(mx, 16));
        mx = fmaxf(mx, __shfl_xor(mx, 32));
        const float mnew = fmaxf(m2, mx);
        const float alpha = exp2f_fast(m2 - mnew);
        m2 = mnew;

        float rs = 0.f;
        #pragma unroll
        for (int t = 0; t < 8; ++t) {
            float p[4];
            s16x4 pk;
            #pragma unroll
            for (int r = 0; r < 4; ++r) {
                p[r] = exp2f_fast(fmaf(sf[t][r], s2, -m2));
                rs += p[r];
                ((short*)&pk)[r] = f2bf(p[r]);
            }
            *(s16x4*)&Ps[wave][l15][t * 16 + quad * 4] = pk;  // kv=16t+quad*4..+3
        }
        rs += __shfl_xor(rs, 16);
        rs += __shfl_xor(rs, 32);
        l_r = l_r * alpha + rs;

        // ---- O^T = O^T*alpha + V^T P^T ----
        #pragma unroll
        for (int t = 0; t < 3; ++t)
            #pragma unroll
            for (int r = 0; r < 4; ++r) of[t][r] *= alpha;

        bf16x8 pb[4];
        #pragma unroll
        for (int s = 0; s < 4; ++s)
            pb[s] = *(const bf16x8*)&Ps[wave][l15][s * 32 + quad * 8];
        #pragma unroll
        for (int t = 0; t < 3; ++t) {
            #pragma unroll
            for (int s = 0; s < 4; ++s) {
                const bf16x8 va = *(const bf16x8*)
                    (vbase + (size_t)t * 16 * 2048 + kt * 128 + s * 32);
                of[t] = __builtin_amdgcn_mfma_f32_16x16x32_bf16(va, pb[s], of[t], 0, 0, 0);
            }
        }
    }

    // ---- epilogue: O^T C-layout col=q=l15, row=d=16t+quad*4+r ----
    const int b = bh >> 3, h = bh & 7;
    const float invl = 1.0f / l_r;
    float* orow = x2 + (size_t)(b * 2048 + q0 + wave * 16 + l15) * 384 + h * 48;
    #pragma unroll
    for (int t = 0; t < 3; ++t) {
        float4 o;
        o.x = of[t][0] * invl;
        o.y = of[t][1] * invl;
        o.z = of[t][2] * invl;
        o.w = of[t][3] * invl;
        *(float4*)(orow + t * 16 + quad * 4) = o;
    }
}

// ---------------------------------------------------------------------------
extern "C" void kernel_launch(void* const* d_in, const int* in_sizes, int n_in,
                              void* d_out, int out_size, void* d_ws, size_t ws_size,
                              hipStream_t stream)
{
    const float* query = (const float*)d_in[0];
    const float* key_  = (const float*)d_in[1];
    const float* value = (const float*)d_in[2];
    const float* Wq = (const float*)d_in[3];
    const float* bq = (const float*)d_in[4];
    const float* Wk = (const float*)d_in[5];
    const float* bk = (const float*)d_in[6];
    const float* Wv = (const float*)d_in[7];
    const float* bv = (const float*)d_in[8];
    const float* Wo = (const float*)d_in[9];
    const float* bo = (const float*)d_in[10];
    const int* qpos = (const int*)d_in[11];
    const int* kpos = (const int*)d_in[12];

    const size_t TC = (size_t)8192 * 384;          // fp32 elems (x2)
    const size_t BF = (size_t)32 * 2048 * 48;      // bf16 elems (q/k/vt each)
    const size_t need = 3 * BF * 2 + TC * 4;       // ~31.5 MB

    short *qbf, *kbf, *vtbf;
    float* x2;
    char* w = (char*)d_ws;
    if (ws_size >= need) {
        qbf  = (short*)w; w += BF * 2;
        kbf  = (short*)w; w += BF * 2;
        vtbf = (short*)w; w += BF * 2;
        x2   = (float*)w;
    } else {
        // qbf lives in d_out (6.3 MB <= 12.6 MB); consumed by attn before the
        // final GEMM overwrites d_out (stream-ordered).
        qbf  = (short*)d_out;
        kbf  = (short*)w; w += BF * 2;
        vtbf = (short*)w; w += BF * 2;
        x2   = (float*)w;
    }

    const dim3 blk(256);
    gemm_qk_rope<<<dim3(128, 6, 2), blk, 0, stream>>>(
        query, key_, Wq, bq, Wk, bk, qpos, kpos, qbf, kbf);
    gemm_v_t<<<dim3(128, 6, 1), blk, 0, stream>>>(value, Wv, bv, vtbf);
    attn_mfma<<<dim3(32, 32, 1), blk, 0, stream>>>(qbf, kbf, vtbf, x2);
    gemm_nt_bias<<<dim3(128, 6, 1), blk, 0, stream>>>(x2, Wo, bo, (float*)d_out);
}